// Round 5
// baseline (268.918 us; speedup 1.0000x reference)
//
#include <hip/hip_runtime.h>

#define KE_CONST 14.3996454784255f

#define P2_SHIFT 14
#define P2_CHUNK 16384            // 64 KB LDS accumulator per chunk
#define NB_BIN   2048             // bin blocks (x4 waves = 8192 wave streams)
#define CAP      128              // records per (wave, bucket) global segment
#define CAP_SHIFT 7
#define RING     128              // LDS ring records per (wave, bucket)
#define B2_ACC   36               // accumulator blocks per chunk
#define MAXC     8

// ---------------- node precompute: { Zf, Zf^0.3, covrad[Z], 0 }; zero out ----------------
__global__ void zbl_node_prep(const float* __restrict__ node_attrs,
                              const int* __restrict__ atomic_numbers,
                              const float* __restrict__ covalent_radii,
                              float4* __restrict__ node_data,
                              float* __restrict__ out_zero_or_null,
                              int n_nodes, int n_elem) {
    int n = blockIdx.x * blockDim.x + threadIdx.x;
    if (n >= n_nodes) return;
    const float* row = node_attrs + (size_t)n * n_elem;
    float best = row[0];
    int bi = 0;
    for (int i = 1; i < n_elem; ++i) {
        float v = row[i];
        if (v > best) { best = v; bi = i; }
    }
    int Z = atomic_numbers[bi];
    float zf = (float)Z;
    float zp = __powf(zf, 0.3f);
    float cr = covalent_radii[Z];
    node_data[n] = make_float4(zf, zp, cr, 0.0f);
    if (out_zero_or_null) out_zero_or_null[n] = 0.0f;
}

// ---------------- per-edge math ----------------
__device__ __forceinline__ float zbl_val(float xv, const float4& du, const float4& dv,
                                         float rmax) {
    const float inv_a_pref = 1.0f / (0.4543f * 0.529f);
    float t = xv * (du.y + dv.y) * inv_a_pref;
    float phi = 0.1818f  * __expf(-3.2f    * t)
              + 0.5099f  * __expf(-0.9423f * t)
              + 0.2802f  * __expf(-0.4028f * t)
              + 0.02817f * __expf(-0.2016f * t);
    float v = KE_CONST * du.x * dv.x * phi / xv;
    float rr = xv / rmax;
    float r2 = rr * rr;
    float r6 = r2 * r2 * r2;
    float env = 1.0f - 28.0f * r6 + 48.0f * r6 * rr - 21.0f * r6 * r2;
    return 0.5f * v * env;
}

// ---------------- pass 1: dense compute + LDS-staged binning, coalesced flushes ----------------
// Wave-private register offsets route records into per-(wave,bucket) LDS rings;
// full 64-record (512 B) aligned bursts go to global. Rare overflow -> atomicAdd(out).
template<int C>
__global__ __launch_bounds__(256)
void zbl_bin3(const float* __restrict__ x,
              const int* __restrict__ ei,
              const float4* __restrict__ nd,
              uint2* __restrict__ pairs,
              unsigned* __restrict__ cnt,
              float* __restrict__ out,
              int n_edges, int W) {
    __shared__ uint2 ring[4][C][RING];

    int wv   = threadIdx.x >> 6;
    int lane = threadIdx.x & 63;
    int wave = (blockIdx.x << 2) + wv;
    long long e0 = (long long)wave * n_edges / W;
    long long e1 = (long long)(wave + 1) * n_edges / W;

    unsigned total[C], flushed[C];
    #pragma unroll
    for (int b = 0; b < C; ++b) { total[b] = 0; flushed[b] = 0; }

    const int* __restrict__ rcv = ei + n_edges;
    unsigned long long lt = (1ULL << lane) - 1ULL;

    for (long long base = e0; base < e1; base += 64) {
        long long e = base + lane;
        bool valid = (e < e1);
        long long ec = valid ? e : (e1 - 1);
        int r = rcv[ec];
        int s = ei[ec];
        float xv = x[ec];
        float4 du = nd[s];
        float4 dv = nd[r];
        float rmax = du.z + dv.z;
        bool keep = valid && (xv < rmax);
        float val = zbl_val(xv, du, dv, rmax);   // dense, once
        int bkt = r >> P2_SHIFT;
        unsigned li = (unsigned)(r & (P2_CHUNK - 1));

        #pragma unroll
        for (int b = 0; b < C; ++b) {
            bool mine = keep && (bkt == b);
            unsigned long long m = __ballot(mine);
            if (m != 0ULL) {
                if (mine) {
                    unsigned rank = total[b] + (unsigned)__popcll(m & lt);
                    ring[wv][b][rank & (RING - 1)] = make_uint2(li, __float_as_uint(val));
                }
                total[b] += (unsigned)__popcll(m);
                if (total[b] - flushed[b] >= 64) {
                    uint2 rec = ring[wv][b][(flushed[b] + lane) & (RING - 1)];
                    unsigned idx = flushed[b] + lane;
                    if (idx < CAP) {
                        pairs[((((size_t)wave * C) + b) << CAP_SHIFT) + idx] = rec;
                    } else {
                        atomicAdd(&out[(b << P2_SHIFT) | rec.x], __uint_as_float(rec.y));
                    }
                    flushed[b] += 64;
                }
            }
        }
    }

    // epilogue: drain residual (<64) per bucket, write counts
    #pragma unroll
    for (int b = 0; b < C; ++b) {
        unsigned pend = total[b] - flushed[b];
        if ((unsigned)lane < pend) {
            uint2 rec = ring[wv][b][(flushed[b] + lane) & (RING - 1)];
            unsigned idx = flushed[b] + lane;
            if (idx < CAP) {
                pairs[((((size_t)wave * C) + b) << CAP_SHIFT) + idx] = rec;
            } else {
                atomicAdd(&out[(b << P2_SHIFT) | rec.x], __uint_as_float(rec.y));
            }
        }
        if (lane == 0) {
            unsigned v = total[b];
            cnt[wave * C + b] = v < CAP ? v : CAP;
        }
    }
}

// ---------------- pass 2: per-wave consumption of segments, LDS accumulate ----------------
__global__ __launch_bounds__(256)
void zbl_accum2(const uint2* __restrict__ pairs,
                const unsigned* __restrict__ cnt,
                float* __restrict__ partial,
                int C, int B2, int W) {
    int c = blockIdx.x / B2;
    int j = blockIdx.x - c * B2;

    __shared__ __align__(16) float acc[P2_CHUNK];
    for (int i = threadIdx.x * 4; i < P2_CHUNK; i += 256 * 4)
        *(float4*)&acc[i] = make_float4(0.f, 0.f, 0.f, 0.f);
    __syncthreads();

    int wv = threadIdx.x >> 6;
    int lane = threadIdx.x & 63;
    int w0 = (int)((long long)j * W / B2);
    int w1 = (int)((long long)(j + 1) * W / B2);

    for (int w = w0 + wv; w < w1; w += 4) {
        unsigned n = cnt[w * C + c];
        const uint2* __restrict__ seg = pairs + (((size_t)w * C + c) << CAP_SHIFT);
        for (unsigned i = lane; i < n; i += 64) {
            uint2 rec = seg[i];
            atomicAdd(&acc[rec.x], __uint_as_float(rec.y));
        }
    }
    __syncthreads();

    float* p = partial + ((size_t)c * B2 + j) * P2_CHUNK;
    for (int i = threadIdx.x * 4; i < P2_CHUNK; i += 256 * 4)
        *(float4*)(p + i) = *(const float4*)&acc[i];
}

// ---------------- pass 3: reduce partials, ADD into out (out holds overflow atomics) ----------------
__global__ void zbl_reduce_p2(const float* __restrict__ partial,
                              float* __restrict__ out,
                              int n_nodes, int B2) {
    int i = blockIdx.x * blockDim.x + threadIdx.x;
    if (i >= n_nodes) return;
    int c = i >> P2_SHIFT;
    int li = i & (P2_CHUNK - 1);
    const float* p = partial + ((size_t)c * B2) * P2_CHUNK + li;
    float s0 = 0.f, s1 = 0.f, s2 = 0.f, s3 = 0.f;
    int j = 0;
    for (; j + 4 <= B2; j += 4) {
        s0 += p[(size_t)(j + 0) * P2_CHUNK];
        s1 += p[(size_t)(j + 1) * P2_CHUNK];
        s2 += p[(size_t)(j + 2) * P2_CHUNK];
        s3 += p[(size_t)(j + 3) * P2_CHUNK];
    }
    for (; j < B2; ++j) s0 += p[(size_t)j * P2_CHUNK];
    out[i] += (s0 + s1) + (s2 + s3);
}

// ---------------- fallback: direct device atomics ----------------
__global__ void zbl_edge_atomic(const float* __restrict__ x,
                                const int* __restrict__ edge_index,
                                const float4* __restrict__ node_data,
                                float* __restrict__ out,
                                int n_edges) {
    int e = blockIdx.x * blockDim.x + threadIdx.x;
    if (e >= n_edges) return;
    int snd = edge_index[e];
    int r = edge_index[n_edges + e];
    float xv = x[e];
    float4 du = node_data[snd];
    float4 dv = node_data[r];
    float rmax = du.z + dv.z;
    if (xv >= rmax) return;
    atomicAdd(&out[r], zbl_val(xv, du, dv, rmax));
}

extern "C" void kernel_launch(void* const* d_in, const int* in_sizes, int n_in,
                              void* d_out, int out_size, void* d_ws, size_t ws_size,
                              hipStream_t stream) {
    const float* x              = (const float*)d_in[0];
    const float* node_attrs     = (const float*)d_in[1];
    const int*   edge_index     = (const int*)d_in[2];
    const int*   atomic_numbers = (const int*)d_in[3];
    const float* covalent_radii = (const float*)d_in[4];
    float* out = (float*)d_out;

    int n_edges = in_sizes[0];
    int n_elem  = in_sizes[3];
    int n_nodes = in_sizes[1] / n_elem;

    float4* node_data = (float4*)d_ws;
    size_t nd_bytes = (((size_t)n_nodes * sizeof(float4)) + 255) & ~(size_t)255;

    int C = (n_nodes + P2_CHUNK - 1) >> P2_SHIFT;
    int W = NB_BIN * 4;
    size_t cnt_bytes   = ((size_t)W * C * sizeof(unsigned) + 255) & ~(size_t)255;
    size_t pairs_bytes = ((((size_t)W * C) << CAP_SHIFT) * sizeof(uint2) + 255) & ~(size_t)255;
    size_t part_bytes  = (size_t)C * B2_ACC * P2_CHUNK * sizeof(float);
    bool fast = (C >= 1) && (C <= MAXC) &&
                (ws_size >= nd_bytes + cnt_bytes + pairs_bytes + part_bytes);

    if (fast) {
        unsigned* cnt   = (unsigned*)((char*)d_ws + nd_bytes);
        uint2*    pairs = (uint2*)((char*)d_ws + nd_bytes + cnt_bytes);
        float*    part  = (float*)((char*)d_ws + nd_bytes + cnt_bytes + pairs_bytes);

        zbl_node_prep<<<(n_nodes + 255) / 256, 256, 0, stream>>>(
            node_attrs, atomic_numbers, covalent_radii, node_data,
            out, n_nodes, n_elem);   // zeroes out (overflow-atomic target)

        switch (C) {
            case 1: zbl_bin3<1><<<NB_BIN, 256, 0, stream>>>(x, edge_index, node_data, pairs, cnt, out, n_edges, W); break;
            case 2: zbl_bin3<2><<<NB_BIN, 256, 0, stream>>>(x, edge_index, node_data, pairs, cnt, out, n_edges, W); break;
            case 3: zbl_bin3<3><<<NB_BIN, 256, 0, stream>>>(x, edge_index, node_data, pairs, cnt, out, n_edges, W); break;
            case 4: zbl_bin3<4><<<NB_BIN, 256, 0, stream>>>(x, edge_index, node_data, pairs, cnt, out, n_edges, W); break;
            case 5: zbl_bin3<5><<<NB_BIN, 256, 0, stream>>>(x, edge_index, node_data, pairs, cnt, out, n_edges, W); break;
            case 6: zbl_bin3<6><<<NB_BIN, 256, 0, stream>>>(x, edge_index, node_data, pairs, cnt, out, n_edges, W); break;
            case 7: zbl_bin3<7><<<NB_BIN, 256, 0, stream>>>(x, edge_index, node_data, pairs, cnt, out, n_edges, W); break;
            default: zbl_bin3<8><<<NB_BIN, 256, 0, stream>>>(x, edge_index, node_data, pairs, cnt, out, n_edges, W); break;
        }

        zbl_accum2<<<C * B2_ACC, 256, 0, stream>>>(pairs, cnt, part, C, B2_ACC, W);
        zbl_reduce_p2<<<(n_nodes + 255) / 256, 256, 0, stream>>>(part, out, n_nodes, B2_ACC);
        return;
    }

    // fallback: plain device atomics
    zbl_node_prep<<<(n_nodes + 255) / 256, 256, 0, stream>>>(
        node_attrs, atomic_numbers, covalent_radii, node_data,
        out, n_nodes, n_elem);
    zbl_edge_atomic<<<(n_edges + 255) / 256, 256, 0, stream>>>(
        x, edge_index, node_data, out, n_edges);
}

// Round 7
// 244.762 us; speedup vs baseline: 1.0987x; 1.0987x over previous
//
#include <hip/hip_runtime.h>

#define KE_CONST 14.3996454784255f

#define P2_SHIFT 15
#define P2_CHUNK 32768            // 128 KB LDS accumulator per chunk (verified working on gfx950)
#define SCAN_B2  64               // blocks per chunk
#define SCAN_THR 1024             // 16 waves/block, 1 block/CU (128 KB LDS)
#define MAXC     4                // packed field: 2-bit chunk + 15-bit li + 15-bit e8m7 value

// ---------------- node precompute: { Zf, Zf^0.3, covrad[Z], 0 } ----------------
__global__ void zbl_node_prep(const float* __restrict__ node_attrs,
                              const int* __restrict__ atomic_numbers,
                              const float* __restrict__ covalent_radii,
                              float4* __restrict__ node_data,
                              float* __restrict__ out_zero_or_null,
                              int n_nodes, int n_elem) {
    int n = blockIdx.x * blockDim.x + threadIdx.x;
    if (n >= n_nodes) return;
    const float* row = node_attrs + (size_t)n * n_elem;
    float best = row[0];
    int bi = 0;
    for (int i = 1; i < n_elem; ++i) {
        float v = row[i];
        if (v > best) { best = v; bi = i; }
    }
    int Z = atomic_numbers[bi];
    float zf = (float)Z;
    float zp = __powf(zf, 0.3f);
    float cr = covalent_radii[Z];
    node_data[n] = make_float4(zf, zp, cr, 0.0f);
    if (out_zero_or_null) out_zero_or_null[n] = 0.0f;
}

// ---------------- per-edge math ----------------
__device__ __forceinline__ float zbl_val(float xv, const float4& du, const float4& dv,
                                         float rmax) {
    const float inv_a_pref = 1.0f / (0.4543f * 0.529f);
    float t = xv * (du.y + dv.y) * inv_a_pref;
    float phi = 0.1818f  * __expf(-3.2f    * t)
              + 0.5099f  * __expf(-0.9423f * t)
              + 0.2802f  * __expf(-0.4028f * t)
              + 0.02817f * __expf(-0.2016f * t);
    float v = KE_CONST * du.x * dv.x * phi / xv;
    float rr = xv / rmax;
    float r2 = rr * rr;
    float r6 = r2 * r2 * r2;
    float env = 1.0f - 28.0f * r6 + 48.0f * r6 * rr - 21.0f * r6 * r2;
    return 0.5f * v * env;
}

// encode: r(17b) << 15 | e8m7(val). val clamped to >= 0 first: the envelope's
// triple-root cancellation at r->1 can yield tiny NEGATIVE floats whose sign
// bit would otherwise hit the clamp and decode to NaN (round-6 bug).
__device__ __forceinline__ unsigned enc_edge(float xv, int s, int r,
                                             const float4* __restrict__ nd) {
    float4 du = nd[s];
    float4 dv = nd[r];
    float rmax = du.z + dv.z;
    unsigned e = 0u;
    if (xv < rmax) {
        float v = fmaxf(zbl_val(xv, du, dv, rmax), 0.0f);
        unsigned b = __float_as_uint(v);
        e = (b + 0x8000u) >> 16;          // bf16-style round-half-up, positive only
        if (e > 0x7FFFu) e = 0x7FFFu;     // unreachable for v in physical range
    }
    return ((unsigned)r << 15) | e;
}

// ---------------- pass 1: dense streaming compute -> packed u32 per edge ----------------
__global__ __launch_bounds__(256)
void zbl_dense(const float* __restrict__ x,
               const int* __restrict__ ei,
               const float4* __restrict__ nd,
               unsigned* __restrict__ packed,
               int n_edges) {
    int t = blockIdx.x * blockDim.x + threadIdx.x;
    int base = t * 4;
    if (base + 4 <= n_edges) {
        int4   s4 = *(const int4*)(ei + base);
        int4   r4 = *(const int4*)(ei + n_edges + base);
        float4 x4 = *(const float4*)(x + base);
        uint4 o;
        o.x = enc_edge(x4.x, s4.x, r4.x, nd);
        o.y = enc_edge(x4.y, s4.y, r4.y, nd);
        o.z = enc_edge(x4.z, s4.z, r4.z, nd);
        o.w = enc_edge(x4.w, s4.w, r4.w, nd);
        *(uint4*)(packed + base) = o;
    } else {
        for (int e = base; e < n_edges; ++e)
            packed[e] = enc_edge(x[e], ei[e], ei[n_edges + e], nd);
    }
}

// ---------------- pass 2: chunked scan of packed records, LDS accumulate ----------------
__global__ __launch_bounds__(SCAN_THR)
void zbl_scan(const unsigned* __restrict__ packed,
              float* __restrict__ partial,
              int n_edges) {
    unsigned c = blockIdx.x >> 6;            // SCAN_B2 = 64
    int      j = blockIdx.x & (SCAN_B2 - 1);

    __shared__ __align__(16) float acc[P2_CHUNK];
    for (int i = threadIdx.x * 4; i < P2_CHUNK; i += SCAN_THR * 4)
        *(float4*)&acc[i] = make_float4(0.f, 0.f, 0.f, 0.f);
    __syncthreads();

    long long e0 = (((long long)j * n_edges) / SCAN_B2) & ~3LL;
    long long e1 = (j == SCAN_B2 - 1) ? (long long)n_edges
                                      : ((((long long)(j + 1) * n_edges) / SCAN_B2) & ~3LL);
    long long vend = e1 & ~3LL;

    for (long long b = e0 + (long long)threadIdx.x * 4; b + 4 <= vend;
         b += (long long)SCAN_THR * 4) {
        uint4 p = *(const uint4*)(packed + b);
        if ((p.x >> 30) == c) atomicAdd(&acc[(p.x >> 15) & (P2_CHUNK - 1)],
                                        __uint_as_float((p.x & 0x7FFFu) << 16));
        if ((p.y >> 30) == c) atomicAdd(&acc[(p.y >> 15) & (P2_CHUNK - 1)],
                                        __uint_as_float((p.y & 0x7FFFu) << 16));
        if ((p.z >> 30) == c) atomicAdd(&acc[(p.z >> 15) & (P2_CHUNK - 1)],
                                        __uint_as_float((p.z & 0x7FFFu) << 16));
        if ((p.w >> 30) == c) atomicAdd(&acc[(p.w >> 15) & (P2_CHUNK - 1)],
                                        __uint_as_float((p.w & 0x7FFFu) << 16));
    }
    // scalar tail (only possible in last block when n_edges % 4 != 0)
    for (long long e = vend + threadIdx.x; e < e1; e += SCAN_THR) {
        unsigned w = packed[e];
        if ((w >> 30) == c) atomicAdd(&acc[(w >> 15) & (P2_CHUNK - 1)],
                                      __uint_as_float((w & 0x7FFFu) << 16));
    }

    __syncthreads();
    float* pp = partial + (size_t)blockIdx.x * P2_CHUNK;
    for (int i = threadIdx.x * 4; i < P2_CHUNK; i += SCAN_THR * 4)
        *(float4*)(pp + i) = *(const float4*)&acc[i];
}

// ---------------- pass 3: reduce SCAN_B2 partials per node, overwrite out ----------------
__global__ void zbl_reduce(const float* __restrict__ partial,
                           float* __restrict__ out,
                           int n_nodes) {
    int i = blockIdx.x * blockDim.x + threadIdx.x;
    if (i >= n_nodes) return;
    int c  = i >> P2_SHIFT;
    int li = i & (P2_CHUNK - 1);
    const float* p = partial + ((size_t)c * SCAN_B2) * P2_CHUNK + li;
    float s0 = 0.f, s1 = 0.f, s2 = 0.f, s3 = 0.f;
    #pragma unroll
    for (int j = 0; j < SCAN_B2; j += 4) {
        s0 += p[(size_t)(j + 0) * P2_CHUNK];
        s1 += p[(size_t)(j + 1) * P2_CHUNK];
        s2 += p[(size_t)(j + 2) * P2_CHUNK];
        s3 += p[(size_t)(j + 3) * P2_CHUNK];
    }
    out[i] = (s0 + s1) + (s2 + s3);
}

// ---------------- fallback: direct device atomics ----------------
__global__ void zbl_edge_atomic(const float* __restrict__ x,
                                const int* __restrict__ edge_index,
                                const float4* __restrict__ node_data,
                                float* __restrict__ out,
                                int n_edges) {
    int e = blockIdx.x * blockDim.x + threadIdx.x;
    if (e >= n_edges) return;
    int snd = edge_index[e];
    int r = edge_index[n_edges + e];
    float xv = x[e];
    float4 du = node_data[snd];
    float4 dv = node_data[r];
    float rmax = du.z + dv.z;
    if (xv >= rmax) return;
    atomicAdd(&out[r], zbl_val(xv, du, dv, rmax));
}

extern "C" void kernel_launch(void* const* d_in, const int* in_sizes, int n_in,
                              void* d_out, int out_size, void* d_ws, size_t ws_size,
                              hipStream_t stream) {
    const float* x              = (const float*)d_in[0];
    const float* node_attrs     = (const float*)d_in[1];
    const int*   edge_index     = (const int*)d_in[2];
    const int*   atomic_numbers = (const int*)d_in[3];
    const float* covalent_radii = (const float*)d_in[4];
    float* out = (float*)d_out;

    int n_edges = in_sizes[0];
    int n_elem  = in_sizes[3];
    int n_nodes = in_sizes[1] / n_elem;

    float4* node_data = (float4*)d_ws;
    size_t nd_bytes = (((size_t)n_nodes * sizeof(float4)) + 255) & ~(size_t)255;

    int C = (n_nodes + P2_CHUNK - 1) >> P2_SHIFT;
    size_t packed_bytes = (((size_t)n_edges * sizeof(unsigned)) + 255) & ~(size_t)255;
    size_t part_bytes   = (size_t)C * SCAN_B2 * P2_CHUNK * sizeof(float);
    bool fast = (C >= 1) && (C <= MAXC) && (n_nodes <= (1 << 17)) &&
                (ws_size >= nd_bytes + packed_bytes + part_bytes);

    if (fast) {
        unsigned* packed = (unsigned*)((char*)d_ws + nd_bytes);
        float*    part   = (float*)((char*)d_ws + nd_bytes + packed_bytes);

        zbl_node_prep<<<(n_nodes + 255) / 256, 256, 0, stream>>>(
            node_attrs, atomic_numbers, covalent_radii, node_data,
            nullptr, n_nodes, n_elem);

        int nthr = (n_edges + 3) / 4;
        zbl_dense<<<(nthr + 255) / 256, 256, 0, stream>>>(
            x, edge_index, node_data, packed, n_edges);

        zbl_scan<<<C * SCAN_B2, SCAN_THR, 0, stream>>>(packed, part, n_edges);

        zbl_reduce<<<(n_nodes + 255) / 256, 256, 0, stream>>>(part, out, n_nodes);
        return;
    }

    // fallback: plain device atomics
    zbl_node_prep<<<(n_nodes + 255) / 256, 256, 0, stream>>>(
        node_attrs, atomic_numbers, covalent_radii, node_data,
        out, n_nodes, n_elem);
    zbl_edge_atomic<<<(n_edges + 255) / 256, 256, 0, stream>>>(
        x, edge_index, node_data, out, n_edges);
}

// Round 8
// 215.099 us; speedup vs baseline: 1.2502x; 1.1379x over previous
//
#include <hip/hip_runtime.h>

#define KE_CONST 14.3996454784255f

#define P2_SHIFT 15
#define P2_CHUNK 32768            // 128 KB LDS accumulator per chunk (verified working on gfx950)
#define SCAN_B2  64               // blocks per chunk
#define SCAN_THR 1024             // 16 waves/block, 1 block/CU (128 KB LDS)
#define MAXC     4                // packed field: 2-bit chunk + 15-bit li + 15-bit e8m7 value

// ---------------- node precompute: { Zf, Zf^0.3, covrad[Z], 0 } ----------------
__global__ void zbl_node_prep(const float* __restrict__ node_attrs,
                              const int* __restrict__ atomic_numbers,
                              const float* __restrict__ covalent_radii,
                              float4* __restrict__ node_data,
                              float* __restrict__ out_zero_or_null,
                              int n_nodes, int n_elem) {
    int n = blockIdx.x * blockDim.x + threadIdx.x;
    if (n >= n_nodes) return;
    const float* row = node_attrs + (size_t)n * n_elem;
    float best = row[0];
    int bi = 0;
    for (int i = 1; i < n_elem; ++i) {
        float v = row[i];
        if (v > best) { best = v; bi = i; }
    }
    int Z = atomic_numbers[bi];
    float zf = (float)Z;
    float zp = __powf(zf, 0.3f);
    float cr = covalent_radii[Z];
    node_data[n] = make_float4(zf, zp, cr, 0.0f);
    if (out_zero_or_null) out_zero_or_null[n] = 0.0f;
}

// ---------------- per-edge math ----------------
__device__ __forceinline__ float zbl_val(float xv, const float4& du, const float4& dv,
                                         float rmax) {
    const float inv_a_pref = 1.0f / (0.4543f * 0.529f);
    float t = xv * (du.y + dv.y) * inv_a_pref;
    float phi = 0.1818f  * __expf(-3.2f    * t)
              + 0.5099f  * __expf(-0.9423f * t)
              + 0.2802f  * __expf(-0.4028f * t)
              + 0.02817f * __expf(-0.2016f * t);
    float v = KE_CONST * du.x * dv.x * phi / xv;
    float rr = xv / rmax;
    float r2 = rr * rr;
    float r6 = r2 * r2 * r2;
    float env = 1.0f - 28.0f * r6 + 48.0f * r6 * rr - 21.0f * r6 * r2;
    return 0.5f * v * env;
}

// branchless encode of the 15-bit e8m7 value field (cull applied as predicate)
__device__ __forceinline__ unsigned enc_val(float xv, const float4& du, const float4& dv) {
    float rmax = du.z + dv.z;
    float v = fmaxf(zbl_val(xv, du, dv, rmax), 0.0f);  // kill tiny negatives at r->1
    unsigned e = (__float_as_uint(v) + 0x8000u) >> 16; // bf16-style round half up
    if (e > 0x7FFFu) e = 0x7FFFu;
    return (xv < rmax) ? e : 0u;
}

// scalar (tail) encode, with receiver field
__device__ __forceinline__ unsigned enc_edge(float xv, int s, int r,
                                             const float4* __restrict__ nd) {
    float4 du = nd[s];
    float4 dv = nd[r];
    return ((unsigned)r << 15) | enc_val(xv, du, dv);
}

// ---------------- pass 1: dense streaming compute -> packed u32 per edge ----------------
// All 8 node gathers hoisted up front as independent loads (MLP): round-7's
// per-edge branchy bodies serialized them (VGPR_Count=16, 8 dependent L2
// round-trips per thread -> latency-bound at VALUBusy 12%).
__global__ __launch_bounds__(256)
void zbl_dense(const float* __restrict__ x,
               const int* __restrict__ ei,
               const float4* __restrict__ nd,
               unsigned* __restrict__ packed,
               int n_edges) {
    int t = blockIdx.x * blockDim.x + threadIdx.x;
    int base = t * 4;
    if (base + 4 <= n_edges) {
        int4   s4 = *(const int4*)(ei + base);
        int4   r4 = *(const int4*)(ei + n_edges + base);
        float4 x4 = *(const float4*)(x + base);
        // 8 independent gathers, all in flight together
        float4 du0 = nd[s4.x];
        float4 du1 = nd[s4.y];
        float4 du2 = nd[s4.z];
        float4 du3 = nd[s4.w];
        float4 dv0 = nd[r4.x];
        float4 dv1 = nd[r4.y];
        float4 dv2 = nd[r4.z];
        float4 dv3 = nd[r4.w];
        uint4 o;
        o.x = ((unsigned)r4.x << 15) | enc_val(x4.x, du0, dv0);
        o.y = ((unsigned)r4.y << 15) | enc_val(x4.y, du1, dv1);
        o.z = ((unsigned)r4.z << 15) | enc_val(x4.z, du2, dv2);
        o.w = ((unsigned)r4.w << 15) | enc_val(x4.w, du3, dv3);
        *(uint4*)(packed + base) = o;
    } else {
        for (int e = base; e < n_edges; ++e)
            packed[e] = enc_edge(x[e], ei[e], ei[n_edges + e], nd);
    }
}

// ---------------- pass 2: chunked scan of packed records, LDS accumulate ----------------
__global__ __launch_bounds__(SCAN_THR)
void zbl_scan(const unsigned* __restrict__ packed,
              float* __restrict__ partial,
              int n_edges) {
    unsigned c = blockIdx.x >> 6;            // SCAN_B2 = 64
    int      j = blockIdx.x & (SCAN_B2 - 1);

    __shared__ __align__(16) float acc[P2_CHUNK];
    for (int i = threadIdx.x * 4; i < P2_CHUNK; i += SCAN_THR * 4)
        *(float4*)&acc[i] = make_float4(0.f, 0.f, 0.f, 0.f);
    __syncthreads();

    long long e0 = (((long long)j * n_edges) / SCAN_B2) & ~3LL;
    long long e1 = (j == SCAN_B2 - 1) ? (long long)n_edges
                                      : ((((long long)(j + 1) * n_edges) / SCAN_B2) & ~3LL);
    long long vend = e1 & ~3LL;

    for (long long b = e0 + (long long)threadIdx.x * 4; b + 4 <= vend;
         b += (long long)SCAN_THR * 4) {
        uint4 p = *(const uint4*)(packed + b);
        if ((p.x >> 30) == c) atomicAdd(&acc[(p.x >> 15) & (P2_CHUNK - 1)],
                                        __uint_as_float((p.x & 0x7FFFu) << 16));
        if ((p.y >> 30) == c) atomicAdd(&acc[(p.y >> 15) & (P2_CHUNK - 1)],
                                        __uint_as_float((p.y & 0x7FFFu) << 16));
        if ((p.z >> 30) == c) atomicAdd(&acc[(p.z >> 15) & (P2_CHUNK - 1)],
                                        __uint_as_float((p.z & 0x7FFFu) << 16));
        if ((p.w >> 30) == c) atomicAdd(&acc[(p.w >> 15) & (P2_CHUNK - 1)],
                                        __uint_as_float((p.w & 0x7FFFu) << 16));
    }
    // scalar tail (only possible in last block when n_edges % 4 != 0)
    for (long long e = vend + threadIdx.x; e < e1; e += SCAN_THR) {
        unsigned w = packed[e];
        if ((w >> 30) == c) atomicAdd(&acc[(w >> 15) & (P2_CHUNK - 1)],
                                      __uint_as_float((w & 0x7FFFu) << 16));
    }

    __syncthreads();
    float* pp = partial + (size_t)blockIdx.x * P2_CHUNK;
    for (int i = threadIdx.x * 4; i < P2_CHUNK; i += SCAN_THR * 4)
        *(float4*)(pp + i) = *(const float4*)&acc[i];
}

// ---------------- pass 3: reduce SCAN_B2 partials per node, overwrite out ----------------
__global__ void zbl_reduce(const float* __restrict__ partial,
                           float* __restrict__ out,
                           int n_nodes) {
    int i = blockIdx.x * blockDim.x + threadIdx.x;
    if (i >= n_nodes) return;
    int c  = i >> P2_SHIFT;
    int li = i & (P2_CHUNK - 1);
    const float* p = partial + ((size_t)c * SCAN_B2) * P2_CHUNK + li;
    float s0 = 0.f, s1 = 0.f, s2 = 0.f, s3 = 0.f;
    #pragma unroll
    for (int j = 0; j < SCAN_B2; j += 4) {
        s0 += p[(size_t)(j + 0) * P2_CHUNK];
        s1 += p[(size_t)(j + 1) * P2_CHUNK];
        s2 += p[(size_t)(j + 2) * P2_CHUNK];
        s3 += p[(size_t)(j + 3) * P2_CHUNK];
    }
    out[i] = (s0 + s1) + (s2 + s3);
}

// ---------------- fallback: direct device atomics ----------------
__global__ void zbl_edge_atomic(const float* __restrict__ x,
                                const int* __restrict__ edge_index,
                                const float4* __restrict__ node_data,
                                float* __restrict__ out,
                                int n_edges) {
    int e = blockIdx.x * blockDim.x + threadIdx.x;
    if (e >= n_edges) return;
    int snd = edge_index[e];
    int r = edge_index[n_edges + e];
    float xv = x[e];
    float4 du = node_data[snd];
    float4 dv = node_data[r];
    float rmax = du.z + dv.z;
    if (xv >= rmax) return;
    atomicAdd(&out[r], zbl_val(xv, du, dv, rmax));
}

extern "C" void kernel_launch(void* const* d_in, const int* in_sizes, int n_in,
                              void* d_out, int out_size, void* d_ws, size_t ws_size,
                              hipStream_t stream) {
    const float* x              = (const float*)d_in[0];
    const float* node_attrs     = (const float*)d_in[1];
    const int*   edge_index     = (const int*)d_in[2];
    const int*   atomic_numbers = (const int*)d_in[3];
    const float* covalent_radii = (const float*)d_in[4];
    float* out = (float*)d_out;

    int n_edges = in_sizes[0];
    int n_elem  = in_sizes[3];
    int n_nodes = in_sizes[1] / n_elem;

    float4* node_data = (float4*)d_ws;
    size_t nd_bytes = (((size_t)n_nodes * sizeof(float4)) + 255) & ~(size_t)255;

    int C = (n_nodes + P2_CHUNK - 1) >> P2_SHIFT;
    size_t packed_bytes = (((size_t)n_edges * sizeof(unsigned)) + 255) & ~(size_t)255;
    size_t part_bytes   = (size_t)C * SCAN_B2 * P2_CHUNK * sizeof(float);
    bool fast = (C >= 1) && (C <= MAXC) && (n_nodes <= (1 << 17)) &&
                (ws_size >= nd_bytes + packed_bytes + part_bytes);

    if (fast) {
        unsigned* packed = (unsigned*)((char*)d_ws + nd_bytes);
        float*    part   = (float*)((char*)d_ws + nd_bytes + packed_bytes);

        zbl_node_prep<<<(n_nodes + 255) / 256, 256, 0, stream>>>(
            node_attrs, atomic_numbers, covalent_radii, node_data,
            nullptr, n_nodes, n_elem);

        int nthr = (n_edges + 3) / 4;
        zbl_dense<<<(nthr + 255) / 256, 256, 0, stream>>>(
            x, edge_index, node_data, packed, n_edges);

        zbl_scan<<<C * SCAN_B2, SCAN_THR, 0, stream>>>(packed, part, n_edges);

        zbl_reduce<<<(n_nodes + 255) / 256, 256, 0, stream>>>(part, out, n_nodes);
        return;
    }

    // fallback: plain device atomics
    zbl_node_prep<<<(n_nodes + 255) / 256, 256, 0, stream>>>(
        node_attrs, atomic_numbers, covalent_radii, node_data,
        out, n_nodes, n_elem);
    zbl_edge_atomic<<<(n_edges + 255) / 256, 256, 0, stream>>>(
        x, edge_index, node_data, out, n_edges);
}